// Round 1
// baseline (427.403 us; speedup 1.0000x reference)
//
#include <hip/hip_runtime.h>

// Ragged segmented attention (flash-style), bf16 MFMA 16x16x32.
// B=4 Q=1024 S=2048 H=32 D=128. Effective KV for query i of batch b:
//   cache[b,0:clen] ++ new[b,0:i+1]  (limit = clen + i + 1), rows i>=qlen -> 0.
// Block: 256 thr (4 waves), QT=64 q-rows (16/wave), KT=32 keys/tile.
// K in LDS row-major XOR-swizzled (G4 fix); V in LDS transposed [D][KT] stride 40;
// P through per-wave LDS (same-wave DS ordering, no barrier).

#define BB 4
#define QQ 1024
#define SS 2048
#define HH 32
#define DD 128
#define QT 64
#define KT 32
#define VST 40
#define PST 40

typedef __attribute__((ext_vector_type(8))) short short8;
typedef __attribute__((ext_vector_type(4))) float f32x4;
typedef __attribute__((ext_vector_type(4))) unsigned short u16x4;

__device__ __forceinline__ unsigned short f2bf(float f) {
    unsigned int u = __builtin_bit_cast(unsigned int, f);
    u += 0x7FFFu + ((u >> 16) & 1u);
    return (unsigned short)(u >> 16);
}

__global__ __launch_bounds__(256)
void segattn(const float* __restrict__ qs, const float* __restrict__ ks,
             const float* __restrict__ vs, const float* __restrict__ kc,
             const float* __restrict__ vc, const int* __restrict__ qlens,
             const int* __restrict__ clens, float* __restrict__ out)
{
    const int qt = blockIdx.x, h = blockIdx.y, b = blockIdx.z;
    const int tid = threadIdx.x, wave = tid >> 6, lane = tid & 63;
    const int g = lane >> 4, lc = lane & 15;
    const int qlen = qlens[b], clen = clens[b];
    const int q0 = qt * QT;

    if (q0 >= qlen) {  // whole tile padded: write zeros (harness poisons d_out)
        f32x4 z = {0.f, 0.f, 0.f, 0.f};
        #pragma unroll
        for (int i2 = 0; i2 < 8; ++i2) {
            int f = tid + i2 * 256;
            int r = f >> 5, d4 = f & 31;
            *(f32x4*)&out[(((size_t)b * QQ + q0 + r) * HH + h) * DD + d4 * 4] = z;
        }
        return;
    }

    alignas(16) __shared__ unsigned short Kl[KT * DD];       // swizzled
    alignas(16) __shared__ unsigned short Vl[DD * VST];      // transposed [d][key]
    alignas(16) __shared__ unsigned short Pl[4][16][PST];    // per-wave P

    // ---- preload Q fragments, pre-scaled by SCALE*log2(e) (softmax in base 2)
    const float psc = 0.08838834764831845f * 1.4426950408889634f;
    const int qrow = q0 + wave * 16 + lc;
    const float* qp = qs + (((size_t)b * QQ + qrow) * HH + h) * DD;
    short8 qf[4];
    #pragma unroll
    for (int c = 0; c < 4; ++c) {
        f32x4 a0 = *(const f32x4*)&qp[c * 32 + g * 8];
        f32x4 a1 = *(const f32x4*)&qp[c * 32 + g * 8 + 4];
        short8 t;
        t[0] = (short)f2bf(a0[0] * psc); t[1] = (short)f2bf(a0[1] * psc);
        t[2] = (short)f2bf(a0[2] * psc); t[3] = (short)f2bf(a0[3] * psc);
        t[4] = (short)f2bf(a1[0] * psc); t[5] = (short)f2bf(a1[1] * psc);
        t[6] = (short)f2bf(a1[2] * psc); t[7] = (short)f2bf(a1[3] * psc);
        qf[c] = t;
    }

    f32x4 o[8];
    #pragma unroll
    for (int n = 0; n < 8; ++n) o[n] = (f32x4){0.f, 0.f, 0.f, 0.f};
    float m_[4] = {-3e38f, -3e38f, -3e38f, -3e38f};
    float l_[4] = {0.f, 0.f, 0.f, 0.f};

    int lim[4];
    #pragma unroll
    for (int qq = 0; qq < 4; ++qq) {
        int i = q0 + wave * 16 + g * 4 + qq;
        lim[qq] = (i < qlen) ? (clen + i + 1) : 0;   // 0 => fully masked row
    }

    const int kmax = clen + min(q0 + QT, qlen);
    const int nt = (kmax + KT - 1) / KT;

    for (int t = 0; t < nt; ++t) {
        const int pbase = t * KT;
        __syncthreads();
        // ---- stage K (swizzled) and V^T (bf16) : 32 keys x 128 d
        #pragma unroll
        for (int it = 0; it < 4; ++it) {
            int f = tid + it * 256;            // 0..1023
            int key = f >> 5, d4 = f & 31;
            int p = pbase + key;
            const float *srck, *srcv;
            if (p < clen) {
                size_t off = (((size_t)b * SS + p) * HH + h) * DD + d4 * 4;
                srck = kc + off; srcv = vc + off;
            } else {
                int idx = p - clen; if (idx > QQ - 1) idx = QQ - 1;  // tail, masked anyway
                size_t off = (((size_t)b * QQ + idx) * HH + h) * DD + d4 * 4;
                srck = ks + off; srcv = vs + off;
            }
            f32x4 kv = *(const f32x4*)srck;
            f32x4 vv = *(const f32x4*)srcv;
            int ei = (key * DD + d4 * 4) ^ ((key & 7) << 3);
            u16x4 kb4 = {f2bf(kv[0]), f2bf(kv[1]), f2bf(kv[2]), f2bf(kv[3])};
            *(u16x4*)&Kl[ei] = kb4;
            int d0 = d4 * 4;
            Vl[(d0 + 0) * VST + key] = f2bf(vv[0]);
            Vl[(d0 + 1) * VST + key] = f2bf(vv[1]);
            Vl[(d0 + 2) * VST + key] = f2bf(vv[2]);
            Vl[(d0 + 3) * VST + key] = f2bf(vv[3]);
        }
        __syncthreads();

        // ---- QK^T : S[16 x 32] per wave
        f32x4 sc0 = {0.f, 0.f, 0.f, 0.f}, sc1 = {0.f, 0.f, 0.f, 0.f};
        #pragma unroll
        for (int c = 0; c < 4; ++c) {
            int i0 = (lc * DD + c * 32 + g * 8) ^ ((lc & 7) << 3);
            int i1 = ((16 + lc) * DD + c * 32 + g * 8) ^ (((16 + lc) & 7) << 3);
            short8 k0 = *(const short8*)&Kl[i0];
            short8 k1 = *(const short8*)&Kl[i1];
            sc0 = __builtin_amdgcn_mfma_f32_16x16x32_bf16(qf[c], k0, sc0, 0, 0, 0);
            sc1 = __builtin_amdgcn_mfma_f32_16x16x32_bf16(qf[c], k1, sc1, 0, 0, 0);
        }

        // ---- mask + online softmax (log2 domain)
        float pr0[4], pr1[4];
        #pragma unroll
        for (int qq = 0; qq < 4; ++qq) {
            float s0 = sc0[qq], s1 = sc1[qq];
            if (pbase + lc >= lim[qq])      s0 = -3e38f;
            if (pbase + 16 + lc >= lim[qq]) s1 = -3e38f;
            float pm = fmaxf(s0, s1);
            #pragma unroll
            for (int d2 = 1; d2 < 16; d2 <<= 1) pm = fmaxf(pm, __shfl_xor(pm, d2));
            float mn = fmaxf(m_[qq], pm);
            float alpha = exp2f(m_[qq] - mn);
            float p0 = exp2f(s0 - mn), p1 = exp2f(s1 - mn);
            float rs = p0 + p1;
            #pragma unroll
            for (int d2 = 1; d2 < 16; d2 <<= 1) rs += __shfl_xor(rs, d2);
            l_[qq] = l_[qq] * alpha + rs;
            m_[qq] = mn;
            pr0[qq] = p0; pr1[qq] = p1;
            #pragma unroll
            for (int n = 0; n < 8; ++n) o[n][qq] *= alpha;
        }

        // ---- P -> per-wave LDS (bf16), then PV
        #pragma unroll
        for (int qq = 0; qq < 4; ++qq) {
            Pl[wave][g * 4 + qq][lc]      = f2bf(pr0[qq]);
            Pl[wave][g * 4 + qq][16 + lc] = f2bf(pr1[qq]);
        }
        short8 pf = *(const short8*)&Pl[wave][lc][g * 8];
        #pragma unroll
        for (int n = 0; n < 8; ++n) {
            short8 vf = *(const short8*)&Vl[(n * 16 + lc) * VST + g * 8];
            o[n] = __builtin_amdgcn_mfma_f32_16x16x32_bf16(pf, vf, o[n], 0, 0, 0);
        }
    }

    // ---- epilogue
    #pragma unroll
    for (int qq = 0; qq < 4; ++qq) {
        int i = q0 + wave * 16 + g * 4 + qq;
        bool val = (i < qlen);
        float inv = val ? (1.0f / l_[qq]) : 0.f;
        size_t ob = (((size_t)b * QQ + i) * HH + h) * DD + lc;
        #pragma unroll
        for (int n = 0; n < 8; ++n)
            out[ob + (size_t)n * 16] = val ? o[n][qq] * inv : 0.f;
    }
}

extern "C" void kernel_launch(void* const* d_in, const int* in_sizes, int n_in,
                              void* d_out, int out_size, void* d_ws, size_t ws_size,
                              hipStream_t stream) {
    const float* qs = (const float*)d_in[0];
    const float* ks = (const float*)d_in[1];
    const float* vs = (const float*)d_in[2];
    const float* kc = (const float*)d_in[3];
    const float* vc = (const float*)d_in[4];
    const int* ql = (const int*)d_in[5];
    const int* cl = (const int*)d_in[6];
    float* o = (float*)d_out;
    dim3 grid(QQ / QT, HH, BB), blk(256, 1, 1);
    hipLaunchKernelGGL(segattn, grid, blk, 0, stream, qs, ks, vs, kc, vc, ql, cl, o);
}